// Round 5
// baseline (151.668 us; speedup 1.0000x reference)
//
#include <hip/hip_runtime.h>
#include <math.h>

#define NN 10000
#define NE 160000
#define CAP 96   // per-node edge bin capacity; deg ~ Poisson(16), +20 sigma
#define EPT 4    // edges per thread in k_edge (LDS reuse: 1 b128 feeds 16 FMA)
// Only the l=0 irrep reaches the output (scal takes cols h*72..h*72+8 of pooled,
// which come solely from node_out[:,:,0]; Y[:,0]==1). l=1/l=2 paths are dead.
//
// Round 5: k_edge processes 4 edges/thread -> LDS instruction count /4
// (R4 was LDS-bound: 4 ds_read_b128 per 16 FMA). k_gather merge made
// -inf-safe (deg<4 nodes would NaN-poison via exp(-inf - -inf)).
//
// Workspace (floats):
//   x      [10000][16]        @ 0
//   q      [10000][2][16]     @ 160000
//   k      [10000][2][16]     @ 480000
//   feat   [10000][16]        @ 800000
//   pooled [16][16]           @ 960000
//   deg    int[10000]         @ 960256   (pooled..deg zeroed together)
//   lgp    [10000][96][2]     @ 970256
//   wxs    [10000][96][2][16] @ 2890256

// x = nf @ We + be ; q[h] = x @ Wq[h] ; k[h] = x @ Wk[h]; zeroes pooled+deg
__global__ __launch_bounds__(256) void k_xqk(const float* __restrict__ nf,
        const float* __restrict__ We, const float* __restrict__ be,
        const float* __restrict__ Wq, const float* __restrict__ Wk,
        float* __restrict__ x, float* __restrict__ q, float* __restrict__ k,
        int* __restrict__ zeroReg) {
    int t = threadIdx.x;
    int gid = blockIdx.x * 256 + t;
    if (gid < 10256) zeroReg[gid] = 0;   // pooled(256f)+deg(10000i), contiguous
    __shared__ float sWe[64 * 16];
    __shared__ float sWq[2 * 16 * 16];
    __shared__ float sWk[2 * 16 * 16];
    __shared__ float sNF[16 * 64];
    __shared__ float sX[16 * 16];
    for (int i = t; i < 1024; i += 256) sWe[i] = We[i];
    for (int i = t; i < 512; i += 256) { sWq[i] = Wq[i]; sWk[i] = Wk[i]; }
    int nodeBase = blockIdx.x * 16;
    for (int i = t; i < 1024; i += 256) {
        int n = nodeBase + (i >> 6);
        sNF[i] = (n < NN) ? nf[n * 64 + (i & 63)] : 0.0f;
    }
    __syncthreads();
    int ln = t >> 4, c = t & 15;
    int n = nodeBase + ln;
    float acc = be[c];
    #pragma unroll 16
    for (int j = 0; j < 64; ++j) acc = fmaf(sNF[ln * 64 + j], sWe[j * 16 + c], acc);
    sX[ln * 16 + c] = acc;
    __syncthreads();
    if (n < NN) {
        x[n * 16 + c] = acc;
        #pragma unroll
        for (int h = 0; h < 2; ++h) {
            float aq = 0.0f, ak = 0.0f;
            #pragma unroll
            for (int j = 0; j < 16; ++j) {
                float xv = sX[ln * 16 + j];
                aq = fmaf(xv, sWq[(h * 16 + j) * 16 + c], aq);
                ak = fmaf(xv, sWk[(h * 16 + j) * 16 + c], ak);
            }
            q[(n * 2 + h) * 16 + c] = aq;
            k[(n * 2 + h) * 16 + c] = ak;
        }
    }
}

// per edge: logits + wv0*x[src]; bin slot tgt*CAP+p. EPT edges per thread.
__global__ __launch_bounds__(256) void k_edge(const float* __restrict__ pos,
        const int* __restrict__ ei,
        const float* __restrict__ q, const float* __restrict__ k,
        const float* __restrict__ W1, const float* __restrict__ b1,
        const float* __restrict__ Wa, const float* __restrict__ Wv,
        const float* __restrict__ x, int* __restrict__ deg,
        float* __restrict__ lgp, float* __restrict__ wxs) {
    __shared__ float sW1[128], sB1[128], sWa[128];
    __shared__ float sV[2048];   // [h][j][c] compacted Wv[:, ::3]
    int t0 = threadIdx.x;
    if (t0 < 128) { sW1[t0] = W1[t0]; sB1[t0] = b1[t0]; sWa[t0] = Wa[t0]; }
    for (int i = t0; i < 2048; i += 256) {
        int h = i >> 10, j = (i >> 4) & 63, c = i & 15;
        sV[i] = Wv[(h * 64 + j) * 48 + 3 * c];
    }
    __syncthreads();
    int base = blockIdx.x * (256 * EPT) + t0;

    int   sv[EPT];
    int   pslot[EPT];
    float fh[EPT][2];
    float dot[EPT][2];
    float L2v[EPT][2];

    #pragma unroll
    for (int kk = 0; kk < EPT; ++kk) {
        int e = base + kk * 256;
        bool val = (e < NE);
        int s = val ? ei[e] : 0;
        int t = val ? ei[NE + e] : 0;
        sv[kk] = s;
        int p = val ? atomicAdd(&deg[t], 1) : CAP;
        pslot[kk] = (p < CAP) ? (t * CAP + p) : -1;
        float dx = pos[t * 3 + 0] - pos[s * 3 + 0];
        float dy = pos[t * 3 + 1] - pos[s * 3 + 1];
        float dz = pos[t * 3 + 2] - pos[s * 3 + 2];
        float d = sqrtf(dx * dx + dy * dy + dz * dz);
        fh[kk][0] = d;
        fh[kk][1] = 1.0f / (d * d);
        const float4* qt = (const float4*)(q + (size_t)t * 32);
        const float4* ks = (const float4*)(k + (size_t)s * 32);
        #pragma unroll
        for (int h = 0; h < 2; ++h) {
            float4 a0 = qt[h * 4 + 0], a1 = qt[h * 4 + 1], a2 = qt[h * 4 + 2], a3 = qt[h * 4 + 3];
            float4 b0 = ks[h * 4 + 0], c1 = ks[h * 4 + 1], c2 = ks[h * 4 + 2], c3 = ks[h * 4 + 3];
            dot[kk][h] = a0.x * b0.x + a0.y * b0.y + a0.z * b0.z + a0.w * b0.w
                       + a1.x * c1.x + a1.y * c1.y + a1.z * c1.z + a1.w * c1.w
                       + a2.x * c2.x + a2.y * c2.y + a2.z * c2.z + a2.w * c2.w
                       + a3.x * c3.x + a3.y * c3.y + a3.z * c3.z + a3.w * c3.w;
        }
    }

    #pragma unroll
    for (int h = 0; h < 2; ++h) {
        float acc[EPT][16];
        float att[EPT];
        #pragma unroll
        for (int kk = 0; kk < EPT; ++kk) {
            att[kk] = 0.0f;
            #pragma unroll
            for (int c = 0; c < 16; ++c) acc[kk][c] = 0.0f;
        }
        const float4* vp = (const float4*)(sV + h * 1024);
        const float* w1b = sW1 + h * 64;
        const float* b1b = sB1 + h * 64;
        const float* wab = sWa + h * 64;
        #pragma unroll 2
        for (int j = 0; j < 64; ++j) {
            float W1j = w1b[j], B1j = b1b[j], Waj = wab[j];
            float hid[EPT];
            #pragma unroll
            for (int kk = 0; kk < EPT; ++kk) {
                hid[kk] = fmaxf(fmaf(fh[kk][h], W1j, B1j), 0.0f);
                att[kk] = fmaf(hid[kk], Waj, att[kk]);
            }
            float4 v0 = vp[j * 4 + 0], v1 = vp[j * 4 + 1], v2 = vp[j * 4 + 2], v3 = vp[j * 4 + 3];
            #pragma unroll
            for (int kk = 0; kk < EPT; ++kk) {
                float hj = hid[kk];
                acc[kk][0]  = fmaf(hj, v0.x, acc[kk][0]);  acc[kk][1]  = fmaf(hj, v0.y, acc[kk][1]);
                acc[kk][2]  = fmaf(hj, v0.z, acc[kk][2]);  acc[kk][3]  = fmaf(hj, v0.w, acc[kk][3]);
                acc[kk][4]  = fmaf(hj, v1.x, acc[kk][4]);  acc[kk][5]  = fmaf(hj, v1.y, acc[kk][5]);
                acc[kk][6]  = fmaf(hj, v1.z, acc[kk][6]);  acc[kk][7]  = fmaf(hj, v1.w, acc[kk][7]);
                acc[kk][8]  = fmaf(hj, v2.x, acc[kk][8]);  acc[kk][9]  = fmaf(hj, v2.y, acc[kk][9]);
                acc[kk][10] = fmaf(hj, v2.z, acc[kk][10]); acc[kk][11] = fmaf(hj, v2.w, acc[kk][11]);
                acc[kk][12] = fmaf(hj, v3.x, acc[kk][12]); acc[kk][13] = fmaf(hj, v3.y, acc[kk][13]);
                acc[kk][14] = fmaf(hj, v3.z, acc[kk][14]); acc[kk][15] = fmaf(hj, v3.w, acc[kk][15]);
            }
        }
        #pragma unroll
        for (int kk = 0; kk < EPT; ++kk) {
            L2v[kk][h] = fmaf(dot[kk][h], 0.25f, att[kk]);
            if (pslot[kk] >= 0) {
                const float4* xp = (const float4*)(x + (size_t)sv[kk] * 16);
                float4 x0 = xp[0], x1 = xp[1], x2 = xp[2], x3 = xp[3];
                float4* wp = (float4*)(wxs + (size_t)pslot[kk] * 32 + h * 16);
                wp[0] = make_float4(acc[kk][0] * x0.x,  acc[kk][1] * x0.y,  acc[kk][2] * x0.z,  acc[kk][3] * x0.w);
                wp[1] = make_float4(acc[kk][4] * x1.x,  acc[kk][5] * x1.y,  acc[kk][6] * x1.z,  acc[kk][7] * x1.w);
                wp[2] = make_float4(acc[kk][8] * x2.x,  acc[kk][9] * x2.y,  acc[kk][10] * x2.z, acc[kk][11] * x2.w);
                wp[3] = make_float4(acc[kk][12] * x3.x, acc[kk][13] * x3.y, acc[kk][14] * x3.z, acc[kk][15] * x3.w);
            }
        }
    }
    #pragma unroll
    for (int kk = 0; kk < EPT; ++kk) {
        if (pslot[kk] >= 0)
            *(float2*)(lgp + (size_t)pslot[kk] * 2) = make_float2(L2v[kk][0], L2v[kk][1]);
    }
}

// wave per (node,head): 4 edge-groups x 16 channels, single-pass online softmax.
__global__ __launch_bounds__(256) void k_gather(const int* __restrict__ deg,
        const float* __restrict__ lgp, const float* __restrict__ wxs,
        const float* __restrict__ Wo, float* __restrict__ feat) {
    __shared__ float sWo[256];     // [h][c][o] = Wo[h*384 + c*8 + o]
    __shared__ float sUn[4][16];
    int t0 = threadIdx.x;
    sWo[t0] = Wo[(t0 >> 7) * 384 + (t0 & 127)];
    __syncthreads();
    int wv = t0 >> 6;                     // wave in block 0..3
    int lane = t0 & 63;
    int pid = blockIdx.x * 4 + wv;        // (node,head) pair; grid exact
    int n = pid >> 1, h = pid & 1;
    int dg = min(deg[n], CAP);
    int g = lane >> 4, c = lane & 15;
    float m = -INFINITY, z = 0.0f, u = 0.0f;
    const float* lgb = lgp + (size_t)n * (CAP * 2) + h;
    const float* wxb = wxs + (size_t)n * (CAP * 32) + h * 16 + c;
    for (int i = g; i < dg; i += 4) {
        float L  = lgb[i * 2];
        float wx = wxb[(size_t)i * 32];
        float nm = fmaxf(m, L);
        float sc = (m > -INFINITY) ? __expf(m - nm) : 0.0f;
        float w  = __expf(L - nm);
        u = fmaf(u, sc, w * wx);
        z = fmaf(z, sc, w);
        m = nm;
    }
    // -inf-safe merge of the 4 groups (lane^16, lane^32 preserve channel bits)
    #pragma unroll
    for (int off = 16; off <= 32; off <<= 1) {
        float mo = __shfl_xor(m, off, 64);
        float zo = __shfl_xor(z, off, 64);
        float uo = __shfl_xor(u, off, 64);
        float nm = fmaxf(m, mo);
        float a = (m  > -INFINITY) ? __expf(m  - nm) : 0.0f;
        float b = (mo > -INFINITY) ? __expf(mo - nm) : 0.0f;
        u = u * a + uo * b;
        z = z * a + zo * b;
        m = nm;
    }
    float un = (z > 0.0f) ? u / z : 0.0f;   // empty node -> 0
    sUn[wv][c] = un;                        // 4 lanes same value, benign
    if (lane < 8) {
        float o_acc = 0.0f;
        #pragma unroll
        for (int cc = 0; cc < 16; ++cc)
            o_acc = fmaf(sUn[wv][cc], sWo[h * 128 + cc * 8 + lane], o_acc);
        feat[n * 16 + h * 8 + lane] = o_acc;
    }
}

// pooled[g][hc] += feat[n][hc] for batch[n]==g; LDS pre-aggregation, 40 blocks
__global__ __launch_bounds__(256) void k_pool(const float* __restrict__ feat,
        const int* __restrict__ batch, float* __restrict__ pooled) {
    __shared__ float sP[256];
    int t = threadIdx.x;
    sP[t] = 0.0f;
    __syncthreads();
    for (int i = blockIdx.x * 256 + t; i < NN * 16; i += 40 * 256) {
        int n = i >> 4, c = i & 15;
        atomicAdd(&sP[batch[n] * 16 + c], feat[i]);
    }
    __syncthreads();
    atomicAdd(&pooled[t], sP[t]);
}

__global__ __launch_bounds__(512) void k_final(const float* __restrict__ pooled,
        const float* __restrict__ Wproj, const float* __restrict__ bproj,
        float* __restrict__ out) {
    int t = threadIdx.x;
    int g = t >> 5, fo = t & 31;
    float acc = bproj[fo];
    #pragma unroll
    for (int j = 0; j < 16; ++j) acc = fmaf(pooled[g * 16 + j], Wproj[j * 32 + fo], acc);
    out[g * 32 + fo] = acc;
}

extern "C" void kernel_launch(void* const* d_in, const int* in_sizes, int n_in,
                              void* d_out, int out_size, void* d_ws, size_t ws_size,
                              hipStream_t stream) {
    const float* nf    = (const float*)d_in[0];
    const float* pos   = (const float*)d_in[1];
    const float* We    = (const float*)d_in[2];
    const float* be    = (const float*)d_in[3];
    const float* Wq    = (const float*)d_in[4];
    const float* Wk    = (const float*)d_in[5];
    const float* W1    = (const float*)d_in[6];
    const float* b1    = (const float*)d_in[7];
    const float* Wa    = (const float*)d_in[8];
    const float* Wv    = (const float*)d_in[9];
    const float* Wo    = (const float*)d_in[10];
    const float* Wproj = (const float*)d_in[11];
    const float* bproj = (const float*)d_in[12];
    const int*   ei    = (const int*)d_in[13];
    const int*   batch = (const int*)d_in[14];
    float* out = (float*)d_out;
    (void)in_sizes; (void)n_in; (void)out_size; (void)ws_size;

    float* ws     = (float*)d_ws;
    float* x      = ws;                  // 160000
    float* q      = x + 160000;          // 320000
    float* k      = q + 320000;          // 320000
    float* feat   = k + 320000;          // 160000
    float* pooled = feat + 160000;       // 256
    int*   deg    = (int*)(pooled + 256);// 10000
    float* lgp    = (float*)(deg + 10000);       // 1,920,000
    float* wxs    = lgp + (size_t)NN * CAP * 2;  // 30,720,000

    hipLaunchKernelGGL(k_xqk,    dim3(625),  dim3(256), 0, stream, nf, We, be, Wq, Wk, x, q, k, (int*)pooled);
    hipLaunchKernelGGL(k_edge,   dim3(157),  dim3(256), 0, stream, pos, ei, q, k, W1, b1, Wa, Wv, x, deg, lgp, wxs);
    hipLaunchKernelGGL(k_gather, dim3(5000), dim3(256), 0, stream, deg, lgp, wxs, Wo, feat);
    hipLaunchKernelGGL(k_pool,   dim3(40),   dim3(256), 0, stream, feat, batch, pooled);
    hipLaunchKernelGGL(k_final,  dim3(1),    dim3(512), 0, stream, pooled, Wproj, bproj, out);
}

// Round 6
// 133.027 us; speedup vs baseline: 1.1401x; 1.1401x over previous
//
#include <hip/hip_runtime.h>
#include <math.h>

#define NN 10000
#define NE 160000
#define CAP 96   // per-node edge bin capacity; deg ~ Poisson(16), +20 sigma
// Only the l=0 irrep reaches the output (scal takes cols h*72..h*72+8 of pooled,
// which come solely from node_out[:,:,0]; Y[:,0]==1). l=1/l=2 paths are dead.
//
// Round 6: R5 post-mortem — EPT=4 killed occupancy (157 blocks, VGPR 188,
// Occ 6%). New approach: weights are wave-uniform -> read V/W1/Wa/Wo via
// lane-invariant indices from __restrict__ global so the compiler emits
// scalar s_loads (SGPR operands), zero LDS, EPT=1 (625 blocks, full TLP).
// Also fold Wo into the edge kernel: payload per (edge,head) is 8 floats
// (g[o]) instead of 16 (wxs) — halves bin traffic, simplifies gather.
//
// Workspace (floats):
//   x      [10000][16]        @ 0
//   q      [10000][2][16]     @ 160000
//   k      [10000][2][16]     @ 480000
//   feat   [10000][16]        @ 800000
//   pooled [16][16]           @ 960000
//   deg    int[10000]         @ 960256   (pooled..deg zeroed together)
//   vC     [2][64][16]        @ 970256   (compacted Wv[:, ::3])
//   lgp    [10000][96][2]     @ 972304
//   gws    [10000][96][2][8]  @ 2892304

// x = nf @ We + be ; q[h] = x @ Wq[h] ; k[h] = x @ Wk[h]
// block 0 also compacts Wv -> vC; all blocks zero pooled+deg.
__global__ __launch_bounds__(256) void k_xqk(const float* __restrict__ nf,
        const float* __restrict__ We, const float* __restrict__ be,
        const float* __restrict__ Wq, const float* __restrict__ Wk,
        const float* __restrict__ Wv,
        float* __restrict__ x, float* __restrict__ q, float* __restrict__ k,
        int* __restrict__ zeroReg, float* __restrict__ vC) {
    int t = threadIdx.x;
    int gid = blockIdx.x * 256 + t;
    if (gid < 10256) zeroReg[gid] = 0;   // pooled(256f)+deg(10000i), contiguous
    if (blockIdx.x == 0) {
        for (int i = t; i < 2048; i += 256) {
            int h = i >> 10, j = (i >> 4) & 63, c = i & 15;
            vC[i] = Wv[(h * 64 + j) * 48 + 3 * c];
        }
    }
    __shared__ float sWe[64 * 16];
    __shared__ float sWq[2 * 16 * 16];
    __shared__ float sWk[2 * 16 * 16];
    __shared__ float sNF[16 * 64];
    __shared__ float sX[16 * 16];
    for (int i = t; i < 1024; i += 256) sWe[i] = We[i];
    for (int i = t; i < 512; i += 256) { sWq[i] = Wq[i]; sWk[i] = Wk[i]; }
    int nodeBase = blockIdx.x * 16;
    for (int i = t; i < 1024; i += 256) {
        int n = nodeBase + (i >> 6);
        sNF[i] = (n < NN) ? nf[n * 64 + (i & 63)] : 0.0f;
    }
    __syncthreads();
    int ln = t >> 4, c = t & 15;
    int n = nodeBase + ln;
    float acc = be[c];
    #pragma unroll 16
    for (int j = 0; j < 64; ++j) acc = fmaf(sNF[ln * 64 + j], sWe[j * 16 + c], acc);
    sX[ln * 16 + c] = acc;
    __syncthreads();
    if (n < NN) {
        x[n * 16 + c] = acc;
        #pragma unroll
        for (int h = 0; h < 2; ++h) {
            float aq = 0.0f, ak = 0.0f;
            #pragma unroll
            for (int j = 0; j < 16; ++j) {
                float xv = sX[ln * 16 + j];
                aq = fmaf(xv, sWq[(h * 16 + j) * 16 + c], aq);
                ak = fmaf(xv, sWk[(h * 16 + j) * 16 + c], ak);
            }
            q[(n * 2 + h) * 16 + c] = aq;
            k[(n * 2 + h) * 16 + c] = ak;
        }
    }
}

// one thread per edge: logits + g[o] = (hid@V) * x[src] @ Wo, bin slot tgt*CAP+p.
// All weight reads are lane-invariant -> scalar s_loads (SGPR operands).
__global__ __launch_bounds__(256) void k_edge(const float* __restrict__ pos,
        const int* __restrict__ ei,
        const float* __restrict__ q, const float* __restrict__ k,
        const float* __restrict__ W1, const float* __restrict__ b1,
        const float* __restrict__ Wa, const float* __restrict__ vC,
        const float* __restrict__ Wo,
        const float* __restrict__ x, int* __restrict__ deg,
        float* __restrict__ lgp, float* __restrict__ gws) {
    int e = blockIdx.x * 256 + threadIdx.x;
    if (e >= NE) return;
    int s = ei[e], t = ei[NE + e];
    int p = atomicAdd(&deg[t], 1);
    bool ok = (p < CAP);
    size_t slot = (size_t)t * CAP + p;
    float dx = pos[t * 3 + 0] - pos[s * 3 + 0];
    float dy = pos[t * 3 + 1] - pos[s * 3 + 1];
    float dz = pos[t * 3 + 2] - pos[s * 3 + 2];
    float d = sqrtf(dx * dx + dy * dy + dz * dz);
    float fh[2] = { d, 1.0f / (d * d) };
    const float4* xp = (const float4*)(x + (size_t)s * 16);
    float4 xs0 = xp[0], xs1 = xp[1], xs2 = xp[2], xs3 = xp[3];
    float xf[16] = { xs0.x, xs0.y, xs0.z, xs0.w, xs1.x, xs1.y, xs1.z, xs1.w,
                     xs2.x, xs2.y, xs2.z, xs2.w, xs3.x, xs3.y, xs3.z, xs3.w };
    float L2v[2];
    #pragma unroll
    for (int h = 0; h < 2; ++h) {
        const float4* qt = (const float4*)(q + (size_t)t * 32 + h * 16);
        const float4* ks = (const float4*)(k + (size_t)s * 32 + h * 16);
        float4 a0 = qt[0], a1 = qt[1], a2 = qt[2], a3 = qt[3];
        float4 b0 = ks[0], c1 = ks[1], c2 = ks[2], c3 = ks[3];
        float dot = a0.x * b0.x + a0.y * b0.y + a0.z * b0.z + a0.w * b0.w
                  + a1.x * c1.x + a1.y * c1.y + a1.z * c1.z + a1.w * c1.w
                  + a2.x * c2.x + a2.y * c2.y + a2.z * c2.z + a2.w * c2.w
                  + a3.x * c3.x + a3.y * c3.y + a3.z * c3.z + a3.w * c3.w;
        float f = fh[h];
        float att = 0.0f;
        float acc[16];
        #pragma unroll
        for (int c = 0; c < 16; ++c) acc[c] = 0.0f;
        const float* w1b = W1 + h * 64;
        const float* b1b = b1 + h * 64;
        const float* wab = Wa + h * 64;
        const float* vcb = vC + h * 1024;
        #pragma unroll 8
        for (int j = 0; j < 64; ++j) {
            float hid = fmaxf(fmaf(f, w1b[j], b1b[j]), 0.0f);   // uniform scalars
            att = fmaf(hid, wab[j], att);
            #pragma unroll
            for (int c = 0; c < 16; ++c)
                acc[c] = fmaf(hid, vcb[j * 16 + c], acc[c]);     // uniform scalars
        }
        L2v[h] = fmaf(dot, 0.25f, att);
        // project to 8 outputs through Wo[h][0] (uniform scalars)
        float g[8];
        #pragma unroll
        for (int o = 0; o < 8; ++o) g[o] = 0.0f;
        const float* wob = Wo + h * 384;   // Wo[h][0][c][o] = Wo[h*384 + c*8 + o]
        #pragma unroll
        for (int c = 0; c < 16; ++c) {
            float axc = acc[c] * xf[c];
            #pragma unroll
            for (int o = 0; o < 8; ++o) g[o] = fmaf(axc, wob[c * 8 + o], g[o]);
        }
        if (ok) {
            float4* gp = (float4*)(gws + slot * 16 + h * 8);
            gp[0] = make_float4(g[0], g[1], g[2], g[3]);
            gp[1] = make_float4(g[4], g[5], g[6], g[7]);
        }
    }
    if (ok) *(float2*)(lgp + slot * 2) = make_float2(L2v[0], L2v[1]);
}

// wave per (node,head): 8 edge-groups x 8 outputs, single-pass online softmax.
__global__ __launch_bounds__(256) void k_gather(const int* __restrict__ deg,
        const float* __restrict__ lgp, const float* __restrict__ gws,
        float* __restrict__ feat) {
    int t0 = threadIdx.x;
    int wv = t0 >> 6;                     // wave in block 0..3
    int lane = t0 & 63;
    int pid = blockIdx.x * 4 + wv;        // (node,head) pair; grid exact
    int n = pid >> 1, h = pid & 1;
    int dg = min(deg[n], CAP);
    int g = lane >> 3, o = lane & 7;
    float m = -INFINITY, z = 0.0f, u = 0.0f;
    const float* lgb = lgp + (size_t)n * (CAP * 2) + h;
    const float* gwb = gws + (size_t)n * (CAP * 16) + h * 8 + o;
    for (int i = g; i < dg; i += 8) {
        float L  = lgb[i * 2];
        float gv = gwb[(size_t)i * 16];
        float nm = fmaxf(m, L);
        float sc = (m > -INFINITY) ? __expf(m - nm) : 0.0f;
        float w  = __expf(L - nm);
        u = fmaf(u, sc, w * gv);
        z = fmaf(z, sc, w);
        m = nm;
    }
    // -inf-safe merge of the 8 groups (xor offs 8/16/32 preserve o bits)
    #pragma unroll
    for (int off = 8; off <= 32; off <<= 1) {
        float mo = __shfl_xor(m, off, 64);
        float zo = __shfl_xor(z, off, 64);
        float uo = __shfl_xor(u, off, 64);
        float nm = fmaxf(m, mo);
        float a = (m  > -INFINITY) ? __expf(m  - nm) : 0.0f;
        float b = (mo > -INFINITY) ? __expf(mo - nm) : 0.0f;
        u = u * a + uo * b;
        z = z * a + zo * b;
        m = nm;
    }
    float un = (z > 0.0f) ? u / z : 0.0f;   // empty node -> 0
    if (lane < 8) feat[n * 16 + h * 8 + o] = un;
}

// pooled[g][hc] += feat[n][hc] for batch[n]==g; LDS pre-aggregation, 40 blocks
__global__ __launch_bounds__(256) void k_pool(const float* __restrict__ feat,
        const int* __restrict__ batch, float* __restrict__ pooled) {
    __shared__ float sP[256];
    int t = threadIdx.x;
    sP[t] = 0.0f;
    __syncthreads();
    for (int i = blockIdx.x * 256 + t; i < NN * 16; i += 40 * 256) {
        int n = i >> 4, c = i & 15;
        atomicAdd(&sP[batch[n] * 16 + c], feat[i]);
    }
    __syncthreads();
    atomicAdd(&pooled[t], sP[t]);
}

__global__ __launch_bounds__(512) void k_final(const float* __restrict__ pooled,
        const float* __restrict__ Wproj, const float* __restrict__ bproj,
        float* __restrict__ out) {
    int t = threadIdx.x;
    int g = t >> 5, fo = t & 31;
    float acc = bproj[fo];
    #pragma unroll
    for (int j = 0; j < 16; ++j) acc = fmaf(pooled[g * 16 + j], Wproj[j * 32 + fo], acc);
    out[g * 32 + fo] = acc;
}

extern "C" void kernel_launch(void* const* d_in, const int* in_sizes, int n_in,
                              void* d_out, int out_size, void* d_ws, size_t ws_size,
                              hipStream_t stream) {
    const float* nf    = (const float*)d_in[0];
    const float* pos   = (const float*)d_in[1];
    const float* We    = (const float*)d_in[2];
    const float* be    = (const float*)d_in[3];
    const float* Wq    = (const float*)d_in[4];
    const float* Wk    = (const float*)d_in[5];
    const float* W1    = (const float*)d_in[6];
    const float* b1    = (const float*)d_in[7];
    const float* Wa    = (const float*)d_in[8];
    const float* Wv    = (const float*)d_in[9];
    const float* Wo    = (const float*)d_in[10];
    const float* Wproj = (const float*)d_in[11];
    const float* bproj = (const float*)d_in[12];
    const int*   ei    = (const int*)d_in[13];
    const int*   batch = (const int*)d_in[14];
    float* out = (float*)d_out;
    (void)in_sizes; (void)n_in; (void)out_size; (void)ws_size;

    float* ws     = (float*)d_ws;
    float* x      = ws;                  // 160000
    float* q      = x + 160000;          // 320000
    float* k      = q + 320000;          // 320000
    float* feat   = k + 320000;          // 160000
    float* pooled = feat + 160000;       // 256
    int*   deg    = (int*)(pooled + 256);// 10000
    float* vC     = (float*)(deg + 10000);       // 2048
    float* lgp    = vC + 2048;                   // 1,920,000
    float* gws    = lgp + (size_t)NN * CAP * 2;  // 15,360,000

    hipLaunchKernelGGL(k_xqk,    dim3(625),  dim3(256), 0, stream, nf, We, be, Wq, Wk, Wv, x, q, k, (int*)pooled, vC);
    hipLaunchKernelGGL(k_edge,   dim3(625),  dim3(256), 0, stream, pos, ei, q, k, W1, b1, Wa, vC, Wo, x, deg, lgp, gws);
    hipLaunchKernelGGL(k_gather, dim3(5000), dim3(256), 0, stream, deg, lgp, gws, feat);
    hipLaunchKernelGGL(k_pool,   dim3(40),   dim3(256), 0, stream, feat, batch, pooled);
    hipLaunchKernelGGL(k_final,  dim3(1),    dim3(512), 0, stream, pooled, Wproj, bproj, out);
}

// Round 7
// 130.002 us; speedup vs baseline: 1.1667x; 1.0233x over previous
//
#include <hip/hip_runtime.h>
#include <math.h>

#define NN 10000
#define NE 160000
#define CAP 96   // per-node edge bin capacity; deg ~ Poisson(16), +20 sigma
// Only the l=0 irrep reaches the output (scal takes cols h*72..h*72+8 of pooled,
// which come solely from node_out[:,:,0]; Y[:,0]==1). l=1/l=2 paths are dead.
//
// Round 7: bf16-packed edge payload (40 B/edge instead of 72), gather with
// 2 outputs/lane unpacking bf16x2, RLE pooling (batch sorted -> few LDS
// atomics). Logits stay fp32 (exp path precision).
//
// Workspace (floats):
//   x      [10000][16]        @ 0
//   q      [10000][2][16]     @ 160000
//   k      [10000][2][16]     @ 480000
//   feat   [10000][16]        @ 800000
//   pooled [16][16]           @ 960000
//   deg    int[10000]         @ 960256   (pooled..deg zeroed together)
//   vC     [2][64][16]        @ 970256   (compacted Wv[:, ::3])
//   lgp    [10000][96][2]     @ 972304   fp32 logits
//   gb     [10000][96][2][4]  uint       bf16x2-packed g[8] per head

__device__ __forceinline__ unsigned bf16pack2(float a, float b) {
    unsigned ua = __float_as_uint(a);
    unsigned ub = __float_as_uint(b);
    ua = ua + 0x7fffu + ((ua >> 16) & 1u);
    ub = ub + 0x7fffu + ((ub >> 16) & 1u);
    return (ua >> 16) | (ub & 0xffff0000u);
}

// x = nf @ We + be ; q[h] = x @ Wq[h] ; k[h] = x @ Wk[h]
// block 0 also compacts Wv -> vC; all blocks zero pooled+deg.
__global__ __launch_bounds__(256) void k_xqk(const float* __restrict__ nf,
        const float* __restrict__ We, const float* __restrict__ be,
        const float* __restrict__ Wq, const float* __restrict__ Wk,
        const float* __restrict__ Wv,
        float* __restrict__ x, float* __restrict__ q, float* __restrict__ k,
        int* __restrict__ zeroReg, float* __restrict__ vC) {
    int t = threadIdx.x;
    int gid = blockIdx.x * 256 + t;
    if (gid < 10256) zeroReg[gid] = 0;   // pooled(256f)+deg(10000i), contiguous
    if (blockIdx.x == 0) {
        for (int i = t; i < 2048; i += 256) {
            int h = i >> 10, j = (i >> 4) & 63, c = i & 15;
            vC[i] = Wv[(h * 64 + j) * 48 + 3 * c];
        }
    }
    __shared__ float sWe[64 * 16];
    __shared__ float sWq[2 * 16 * 16];
    __shared__ float sWk[2 * 16 * 16];
    __shared__ float sNF[16 * 64];
    __shared__ float sX[16 * 16];
    for (int i = t; i < 1024; i += 256) sWe[i] = We[i];
    for (int i = t; i < 512; i += 256) { sWq[i] = Wq[i]; sWk[i] = Wk[i]; }
    int nodeBase = blockIdx.x * 16;
    for (int i = t; i < 1024; i += 256) {
        int n = nodeBase + (i >> 6);
        sNF[i] = (n < NN) ? nf[n * 64 + (i & 63)] : 0.0f;
    }
    __syncthreads();
    int ln = t >> 4, c = t & 15;
    int n = nodeBase + ln;
    float acc = be[c];
    #pragma unroll 16
    for (int j = 0; j < 64; ++j) acc = fmaf(sNF[ln * 64 + j], sWe[j * 16 + c], acc);
    sX[ln * 16 + c] = acc;
    __syncthreads();
    if (n < NN) {
        x[n * 16 + c] = acc;
        #pragma unroll
        for (int h = 0; h < 2; ++h) {
            float aq = 0.0f, ak = 0.0f;
            #pragma unroll
            for (int j = 0; j < 16; ++j) {
                float xv = sX[ln * 16 + j];
                aq = fmaf(xv, sWq[(h * 16 + j) * 16 + c], aq);
                ak = fmaf(xv, sWk[(h * 16 + j) * 16 + c], ak);
            }
            q[(n * 2 + h) * 16 + c] = aq;
            k[(n * 2 + h) * 16 + c] = ak;
        }
    }
}

// one thread per edge: logits + g[o] = ((hid@V) * x[src]) @ Wo, bin slot tgt*CAP+p.
// Weight reads are lane-invariant -> scalar s_loads. Payload bf16x2-packed.
__global__ __launch_bounds__(256) void k_edge(const float* __restrict__ pos,
        const int* __restrict__ ei,
        const float* __restrict__ q, const float* __restrict__ k,
        const float* __restrict__ W1, const float* __restrict__ b1,
        const float* __restrict__ Wa, const float* __restrict__ vC,
        const float* __restrict__ Wo,
        const float* __restrict__ x, int* __restrict__ deg,
        float* __restrict__ lgp, uint4* __restrict__ gb) {
    int e = blockIdx.x * 256 + threadIdx.x;
    if (e >= NE) return;
    int s = ei[e], t = ei[NE + e];
    int p = atomicAdd(&deg[t], 1);
    bool ok = (p < CAP);
    size_t slot = (size_t)t * CAP + p;
    float dx = pos[t * 3 + 0] - pos[s * 3 + 0];
    float dy = pos[t * 3 + 1] - pos[s * 3 + 1];
    float dz = pos[t * 3 + 2] - pos[s * 3 + 2];
    float d = sqrtf(dx * dx + dy * dy + dz * dz);
    float fh[2] = { d, 1.0f / (d * d) };
    const float4* xp = (const float4*)(x + (size_t)s * 16);
    float4 xs0 = xp[0], xs1 = xp[1], xs2 = xp[2], xs3 = xp[3];
    float xf[16] = { xs0.x, xs0.y, xs0.z, xs0.w, xs1.x, xs1.y, xs1.z, xs1.w,
                     xs2.x, xs2.y, xs2.z, xs2.w, xs3.x, xs3.y, xs3.z, xs3.w };
    float L2v[2];
    #pragma unroll
    for (int h = 0; h < 2; ++h) {
        const float4* qt = (const float4*)(q + (size_t)t * 32 + h * 16);
        const float4* ks = (const float4*)(k + (size_t)s * 32 + h * 16);
        float4 a0 = qt[0], a1 = qt[1], a2 = qt[2], a3 = qt[3];
        float4 b0 = ks[0], c1 = ks[1], c2 = ks[2], c3 = ks[3];
        float dot = a0.x * b0.x + a0.y * b0.y + a0.z * b0.z + a0.w * b0.w
                  + a1.x * c1.x + a1.y * c1.y + a1.z * c1.z + a1.w * c1.w
                  + a2.x * c2.x + a2.y * c2.y + a2.z * c2.z + a2.w * c2.w
                  + a3.x * c3.x + a3.y * c3.y + a3.z * c3.z + a3.w * c3.w;
        float f = fh[h];
        float att = 0.0f;
        float acc[16];
        #pragma unroll
        for (int c = 0; c < 16; ++c) acc[c] = 0.0f;
        const float* w1b = W1 + h * 64;
        const float* b1b = b1 + h * 64;
        const float* wab = Wa + h * 64;
        const float* vcb = vC + h * 1024;
        #pragma unroll 8
        for (int j = 0; j < 64; ++j) {
            float hid = fmaxf(fmaf(f, w1b[j], b1b[j]), 0.0f);   // uniform scalars
            att = fmaf(hid, wab[j], att);
            #pragma unroll
            for (int c = 0; c < 16; ++c)
                acc[c] = fmaf(hid, vcb[j * 16 + c], acc[c]);     // uniform scalars
        }
        L2v[h] = fmaf(dot, 0.25f, att);
        // project to 8 outputs through Wo[h][0] (uniform scalars)
        float g[8];
        #pragma unroll
        for (int o = 0; o < 8; ++o) g[o] = 0.0f;
        const float* wob = Wo + h * 384;   // Wo[h][0][c][o] = Wo[h*384 + c*8 + o]
        #pragma unroll
        for (int c = 0; c < 16; ++c) {
            float axc = acc[c] * xf[c];
            #pragma unroll
            for (int o = 0; o < 8; ++o) g[o] = fmaf(axc, wob[c * 8 + o], g[o]);
        }
        if (ok) {
            gb[slot * 2 + h] = make_uint4(bf16pack2(g[0], g[1]), bf16pack2(g[2], g[3]),
                                          bf16pack2(g[4], g[5]), bf16pack2(g[6], g[7]));
        }
    }
    if (ok) *(float2*)(lgp + slot * 2) = make_float2(L2v[0], L2v[1]);
}

// wave per (node,head): 16 edge-groups x 4 lanes x 2 outputs (bf16x2 unpack),
// single-pass online softmax, -inf-safe merges.
__global__ __launch_bounds__(256) void k_gather(const int* __restrict__ deg,
        const float* __restrict__ lgp, const unsigned* __restrict__ gb,
        float* __restrict__ feat) {
    int t0 = threadIdx.x;
    int wv = t0 >> 6;                     // wave in block 0..3
    int lane = t0 & 63;
    int pid = blockIdx.x * 4 + wv;        // (node,head) pair; grid exact
    int n = pid >> 1, h = pid & 1;
    int dg = min(deg[n], CAP);
    int g = lane >> 2, p = lane & 3;      // group 0..15, uint index 0..3
    float m = -INFINITY, z = 0.0f, u0 = 0.0f, u1 = 0.0f;
    const float* lgb = lgp + (size_t)n * (CAP * 2) + h;
    const unsigned* gbb = gb + (size_t)n * (CAP * 8) + h * 4 + p;
    for (int i = g; i < dg; i += 16) {
        float L = lgb[i * 2];
        unsigned wbits = gbb[(size_t)i * 8];
        float ga = __uint_as_float(wbits << 16);
        float gbv = __uint_as_float(wbits & 0xffff0000u);
        float nm = fmaxf(m, L);
        float sc = (m > -INFINITY) ? __expf(m - nm) : 0.0f;
        float w  = __expf(L - nm);
        u0 = fmaf(u0, sc, w * ga);
        u1 = fmaf(u1, sc, w * gbv);
        z  = fmaf(z, sc, w);
        m = nm;
    }
    // merge the 16 groups (xor offs 4..32 preserve p bits)
    #pragma unroll
    for (int off = 4; off <= 32; off <<= 1) {
        float mo = __shfl_xor(m, off, 64);
        float zo = __shfl_xor(z, off, 64);
        float a0o = __shfl_xor(u0, off, 64);
        float a1o = __shfl_xor(u1, off, 64);
        float nm = fmaxf(m, mo);
        float a = (m  > -INFINITY) ? __expf(m  - nm) : 0.0f;
        float b = (mo > -INFINITY) ? __expf(mo - nm) : 0.0f;
        u0 = u0 * a + a0o * b;
        u1 = u1 * a + a1o * b;
        z  = z * a + zo * b;
        m = nm;
    }
    if (lane < 4) {
        float inv = (z > 0.0f) ? 1.0f / z : 0.0f;
        *(float2*)(feat + n * 16 + h * 8 + p * 2) = make_float2(u0 * inv, u1 * inv);
    }
}

// pooled[g][hc] += feat[n][hc]; run-length accumulation (batch sorted).
// thread = (segment of 16 nodes, channel); 40 blocks x 256.
__global__ __launch_bounds__(256) void k_pool(const float* __restrict__ feat,
        const int* __restrict__ batch, float* __restrict__ pooled) {
    __shared__ float sP[256];
    int t = threadIdx.x;
    sP[t] = 0.0f;
    __syncthreads();
    int tid = blockIdx.x * 256 + t;        // 0..10239
    int c = tid & 15, seg = tid >> 4;      // seg 0..639
    int n0 = seg * 16, n1 = min(n0 + 16, NN);
    float run = 0.0f;
    int curg = -1;
    for (int n = n0; n < n1; ++n) {
        int gg = batch[n];
        if (gg != curg) {
            if (curg >= 0) atomicAdd(&sP[curg * 16 + c], run);
            run = 0.0f; curg = gg;
        }
        run += feat[n * 16 + c];
    }
    if (curg >= 0) atomicAdd(&sP[curg * 16 + c], run);
    __syncthreads();
    atomicAdd(&pooled[t], sP[t]);
}

__global__ __launch_bounds__(512) void k_final(const float* __restrict__ pooled,
        const float* __restrict__ Wproj, const float* __restrict__ bproj,
        float* __restrict__ out) {
    int t = threadIdx.x;
    int g = t >> 5, fo = t & 31;
    float acc = bproj[fo];
    #pragma unroll
    for (int j = 0; j < 16; ++j) acc = fmaf(pooled[g * 16 + j], Wproj[j * 32 + fo], acc);
    out[g * 32 + fo] = acc;
}

extern "C" void kernel_launch(void* const* d_in, const int* in_sizes, int n_in,
                              void* d_out, int out_size, void* d_ws, size_t ws_size,
                              hipStream_t stream) {
    const float* nf    = (const float*)d_in[0];
    const float* pos   = (const float*)d_in[1];
    const float* We    = (const float*)d_in[2];
    const float* be    = (const float*)d_in[3];
    const float* Wq    = (const float*)d_in[4];
    const float* Wk    = (const float*)d_in[5];
    const float* W1    = (const float*)d_in[6];
    const float* b1    = (const float*)d_in[7];
    const float* Wa    = (const float*)d_in[8];
    const float* Wv    = (const float*)d_in[9];
    const float* Wo    = (const float*)d_in[10];
    const float* Wproj = (const float*)d_in[11];
    const float* bproj = (const float*)d_in[12];
    const int*   ei    = (const int*)d_in[13];
    const int*   batch = (const int*)d_in[14];
    float* out = (float*)d_out;
    (void)in_sizes; (void)n_in; (void)out_size; (void)ws_size;

    float* ws     = (float*)d_ws;
    float* x      = ws;                  // 160000
    float* q      = x + 160000;          // 320000
    float* k      = q + 320000;          // 320000
    float* feat   = k + 320000;          // 160000
    float* pooled = feat + 160000;       // 256
    int*   deg    = (int*)(pooled + 256);// 10000
    float* vC     = (float*)(deg + 10000);       // 2048
    float* lgp    = vC + 2048;                   // 1,920,000
    unsigned* gbu = (unsigned*)(lgp + (size_t)NN * CAP * 2);  // 7,680,000 uints

    hipLaunchKernelGGL(k_xqk,    dim3(625),  dim3(256), 0, stream, nf, We, be, Wq, Wk, Wv, x, q, k, (int*)pooled, vC);
    hipLaunchKernelGGL(k_edge,   dim3(625),  dim3(256), 0, stream, pos, ei, q, k, W1, b1, Wa, vC, Wo, x, deg, lgp, (uint4*)gbu);
    hipLaunchKernelGGL(k_gather, dim3(5000), dim3(256), 0, stream, deg, lgp, gbu, feat);
    hipLaunchKernelGGL(k_pool,   dim3(40),   dim3(256), 0, stream, feat, batch, pooled);
    hipLaunchKernelGGL(k_final,  dim3(1),    dim3(512), 0, stream, pooled, Wproj, bproj, out);
}